// Round 2
// baseline (293.907 us; speedup 1.0000x reference)
//
#include <hip/hip_runtime.h>
#include <stdint.h>

typedef __attribute__((ext_vector_type(4))) float f32x4;
typedef __attribute__((ext_vector_type(8))) __bf16 bf16x8;

__device__ __forceinline__ unsigned short f2bf(float f) {
  union { float f; unsigned u; } v; v.f = f;
  unsigned r = v.u + 0x7FFF + ((v.u >> 16) & 1);
  return (unsigned short)(r >> 16);
}

__device__ __forceinline__ void g2l16(const void* g, void* l) {
  __builtin_amdgcn_global_load_lds((const __attribute__((address_space(1))) void*)g,
                                   (__attribute__((address_space(3))) void*)l, 16, 0, 0);
}

// ---------------- weight fp32 -> bf16 ----------------
__global__ void cvt_weights(const float* __restrict__ a, const float* __restrict__ p,
                            unsigned short* __restrict__ wa, unsigned short* __restrict__ wp) {
  int i = blockIdx.x * 256 + threadIdx.x;
  if (i < 786432) wa[i] = f2bf(a[i]);
  else wp[i - 786432] = f2bf(p[i - 786432]);
}

// ---------------- groupnorm stats: one block per (b,g) ----------------
__global__ void gn_stats(const float* __restrict__ x, float* __restrict__ stats) {
  int bid = blockIdx.x;  // b*8+g
  const float4* p = (const float4*)(x + (size_t)bid * 65536);
  float s = 0.f, ss = 0.f;
  for (int i = threadIdx.x; i < 16384; i += 256) {
    float4 v = p[i];
    s += v.x + v.y + v.z + v.w;
    ss += v.x * v.x + v.y * v.y + v.z * v.z + v.w * v.w;
  }
#pragma unroll
  for (int o = 32; o > 0; o >>= 1) {
    s += __shfl_down(s, o, 64);
    ss += __shfl_down(ss, o, 64);
  }
  __shared__ float red[8];
  int w = threadIdx.x >> 6;
  if ((threadIdx.x & 63) == 0) { red[w] = s; red[4 + w] = ss; }
  __syncthreads();
  if (threadIdx.x == 0) {
    s = red[0] + red[1] + red[2] + red[3];
    ss = red[4] + red[5] + red[6] + red[7];
    float mean = s * (1.f / 65536.f);
    float var = ss * (1.f / 65536.f) - mean * mean;
    stats[2 * bid] = mean;
    stats[2 * bid + 1] = rsqrtf(var + 1e-5f);
  }
}

// ---------------- normalize + transpose to xnT[b][p][c] bf16 ----------------
__global__ void gn_norm_t(const float* __restrict__ x, const float* __restrict__ stats,
                          const float* __restrict__ gw, const float* __restrict__ gb,
                          unsigned short* __restrict__ xnT) {
  __shared__ float tile[64][65];
  int bid = blockIdx.x;
  int pt = bid & 15, ct = (bid >> 4) & 7, b = bid >> 7;
  int t = threadIdx.x;
  float mean = stats[2 * (b * 8 + ct)];
  float rstd = stats[2 * (b * 8 + ct) + 1];
  const float* src = x + ((size_t)(b * 512 + ct * 64)) * 1024 + pt * 64;
#pragma unroll
  for (int i = 0; i < 4; i++) {
    int lin = t + i * 256;         // 0..1023
    int c = lin >> 4, p4 = lin & 15;
    float4 v = *(const float4*)(src + (size_t)c * 1024 + p4 * 4);
    float g = gw[ct * 64 + c] * rstd;
    float bb = gb[ct * 64 + c] - mean * g;
    tile[c][p4 * 4 + 0] = v.x * g + bb;
    tile[c][p4 * 4 + 1] = v.y * g + bb;
    tile[c][p4 * 4 + 2] = v.z * g + bb;
    tile[c][p4 * 4 + 3] = v.w * g + bb;
  }
  __syncthreads();
  unsigned short* dst = xnT + ((size_t)b * 1024 + pt * 64) * 512 + ct * 64;
#pragma unroll
  for (int i = 0; i < 4; i++) {
    int lin = t + i * 256;
    int p = lin >> 4, cq = lin & 15;
    ushort4 o;
    o.x = f2bf(tile[cq * 4 + 0][p]);
    o.y = f2bf(tile[cq * 4 + 1][p]);
    o.z = f2bf(tile[cq * 4 + 2][p]);
    o.w = f2bf(tile[cq * 4 + 3][p]);
    *(ushort4*)(dst + (size_t)p * 512 + cq * 4) = o;
  }
}

// ---------------- row softmax, in-place fp32 -> bf16 (stride 2048 elems) ----------------
__global__ void softmax_rows(float* __restrict__ S) {
  size_t row = blockIdx.x;
  float* s = S + row * 1024;
  int t = threadIdx.x;
  float4 v = *(const float4*)(s + t * 4);
  const float scale = 0.04419417382415922f;  // 1/sqrt(512)
  float m = fmaxf(fmaxf(v.x, v.y), fmaxf(v.z, v.w));
#pragma unroll
  for (int o = 32; o > 0; o >>= 1) m = fmaxf(m, __shfl_down(m, o, 64));
  __shared__ float red[8];
  int w = t >> 6;
  if ((t & 63) == 0) red[w] = m;
  __syncthreads();
  m = fmaxf(fmaxf(red[0], red[1]), fmaxf(red[2], red[3]));
  float e0 = __expf((v.x - m) * scale);
  float e1 = __expf((v.y - m) * scale);
  float e2 = __expf((v.z - m) * scale);
  float e3 = __expf((v.w - m) * scale);
  float sum = e0 + e1 + e2 + e3;
#pragma unroll
  for (int o = 32; o > 0; o >>= 1) sum += __shfl_down(sum, o, 64);
  if ((t & 63) == 0) red[4 + w] = sum;
  __syncthreads();
  sum = red[4] + red[5] + red[6] + red[7];
  float inv = 1.0f / sum;
  unsigned short* p = (unsigned short*)s;
  ushort4 o4;
  o4.x = f2bf(e0 * inv); o4.y = f2bf(e1 * inv);
  o4.z = f2bf(e2 * inv); o4.w = f2bf(e3 * inv);
  *(ushort4*)(p + t * 4) = o4;
}

// ---------------- generic bf16 B^T GEMM: C[m,n] = sum_k A[m,k]*B[n,k] ----------------
// EPI: 0=none, 1=+bias[n], 2=+bias[m], 3=+bias[m]+res
template <int EPI, bool OUT_BF16>
__global__ __launch_bounds__(256) void gemm_bt(
    const unsigned short* __restrict__ A, int lda, long long sA,
    const unsigned short* __restrict__ B, int ldb, long long sB,
    void* __restrict__ Cv, int ldc, long long sC,
    const float* __restrict__ bias,
    const float* __restrict__ res, long long sRes,
    int M, int N, int K, int mt, int nt) {
  __shared__ __align__(16) unsigned short As[128 * 32];
  __shared__ __align__(16) unsigned short Bs[128 * 32];
  int bid = blockIdx.x;
  int per = mt * nt;
  int b = bid / per;
  int r = bid % per;
  int mi = r / nt, ni = r % nt;
  int t = threadIdx.x;
  int l = t & 63, w = t >> 6;
  int wm = w >> 1, wn = w & 1;
  int fr = l & 15;
  int fk = (l >> 4) << 3;
  const unsigned short* Ab = A + (size_t)b * sA + (size_t)(mi * 128) * lda;
  const unsigned short* Bb = B + (size_t)b * sB + (size_t)(ni * 128) * ldb;
  int sr = t >> 2, sk = (t & 3) << 3;
  const unsigned short* gA = Ab + (size_t)sr * lda + sk;
  const unsigned short* gB = Bb + (size_t)sr * ldb + sk;
  unsigned short* lA = As + w * 512;  // wave-uniform LDS dest
  unsigned short* lB = Bs + w * 512;
  const unsigned short* ra = As + (wm * 64 + fr) * 32 + fk;
  const unsigned short* rb = Bs + (wn * 64 + fr) * 32 + fk;
  f32x4 acc[4][4] = {};
  for (int k0 = 0; k0 < K; k0 += 32) {
    g2l16(gA, lA);
    g2l16(gA + (size_t)64 * lda, lA + 2048);
    g2l16(gB, lB);
    g2l16(gB + (size_t)64 * ldb, lB + 2048);
    gA += 32; gB += 32;
    __syncthreads();
    bf16x8 af[4], bv[4];
#pragma unroll
    for (int i = 0; i < 4; i++) af[i] = *(const bf16x8*)(ra + i * 512);
#pragma unroll
    for (int j = 0; j < 4; j++) bv[j] = *(const bf16x8*)(rb + j * 512);
#pragma unroll
    for (int i = 0; i < 4; i++)
#pragma unroll
      for (int j = 0; j < 4; j++)
        acc[i][j] = __builtin_amdgcn_mfma_f32_16x16x32_bf16(af[i], bv[j], acc[i][j], 0, 0, 0);
    __syncthreads();
  }
  int crow0 = mi * 128 + wm * 64;
  int ccol0 = ni * 128 + wn * 64;
  int lr = (l >> 4) << 2;
  int lc = l & 15;
#pragma unroll
  for (int i = 0; i < 4; i++) {
#pragma unroll
    for (int j = 0; j < 4; j++) {
      int col = ccol0 + j * 16 + lc;
      float bn = (EPI == 1) ? bias[col] : 0.0f;
#pragma unroll
      for (int e = 0; e < 4; e++) {
        int row = crow0 + i * 16 + lr + e;
        float v = acc[i][j][e];
        if (EPI == 1) v += bn;
        if (EPI == 2 || EPI == 3) v += bias[row];
        if (EPI == 3) v += res[(size_t)b * sRes + (size_t)row * ldc + col];
        size_t o = (size_t)b * sC + (size_t)row * ldc + col;
        if (OUT_BF16) ((unsigned short*)Cv)[o] = f2bf(v);
        else ((float*)Cv)[o] = v;
      }
    }
  }
}

extern "C" void kernel_launch(void* const* d_in, const int* in_sizes, int n_in,
                              void* d_out, int out_size, void* d_ws, size_t ws_size,
                              hipStream_t stream) {
  const float* x = (const float*)d_in[0];
  const float* norm_w = (const float*)d_in[1];
  const float* norm_b = (const float*)d_in[2];
  const float* qkv_w = (const float*)d_in[3];
  const float* qkv_b = (const float*)d_in[4];
  const float* proj_w = (const float*)d_in[5];
  const float* proj_b = (const float*)d_in[6];
  float* out = (float*)d_out;
  char* ws = (char*)d_ws;

  size_t off = 0;
  auto alloc = [&](size_t bytes) {
    off = (off + 255) & ~(size_t)255;
    size_t r = off; off += bytes; return r;
  };
  unsigned short* wqkv  = (unsigned short*)(ws + alloc((size_t)1536 * 512 * 2));
  unsigned short* wproj = (unsigned short*)(ws + alloc((size_t)512 * 512 * 2));
  float* stats          = (float*)(ws + alloc(128 * 2 * 4));
  unsigned short* xnT   = (unsigned short*)(ws + alloc((size_t)16 * 1024 * 512 * 2));
  unsigned short* qkT   = (unsigned short*)(ws + alloc((size_t)16 * 1024 * 1024 * 2)); // reused for Ot
  unsigned short* vbuf  = (unsigned short*)(ws + alloc((size_t)16 * 512 * 1024 * 2));
  float* Sbuf           = (float*)(ws + alloc((size_t)16 * 1024 * 1024 * 4)); // P aliases (stride 2048)

  cvt_weights<<<4096, 256, 0, stream>>>(qkv_w, proj_w, wqkv, wproj);
  gn_stats<<<128, 256, 0, stream>>>(x, stats);
  gn_norm_t<<<2048, 256, 0, stream>>>(x, stats, norm_w, norm_b, xnT);

  // GEMM1: qkT[b][p][o] = sum_c xnT[b][p][c] * wqkv[o][c] + qkv_b[o], o in [0,1024)
  gemm_bt<1, true><<<1024, 256, 0, stream>>>(
      xnT, 512, 1024LL * 512, wqkv, 512, 0,
      qkT, 1024, 1024LL * 1024, qkv_b, nullptr, 0, 1024, 1024, 512, 8, 8);

  // GEMM2: v[b][c][p] = sum_cc wv[c][cc] * xnT[b][p][cc] + qkv_b[1024+c]
  gemm_bt<2, true><<<512, 256, 0, stream>>>(
      wqkv + (size_t)1024 * 512, 512, 0, xnT, 512, 1024LL * 512,
      vbuf, 1024, 512LL * 1024, qkv_b + 1024, nullptr, 0, 512, 1024, 512, 4, 8);

  // GEMM3: S[b][i][j] = sum_c qkT[b][i][c] * qkT[b][j][512+c]   (fp32)
  gemm_bt<0, false><<<1024, 256, 0, stream>>>(
      qkT, 1024, 1024LL * 1024, qkT + 512, 1024, 1024LL * 1024,
      Sbuf, 1024, 1024LL * 1024, nullptr, nullptr, 0, 1024, 1024, 512, 8, 8);

  softmax_rows<<<16384, 256, 0, stream>>>(Sbuf);

  // GEMM4: Ot[b][i][c] = sum_j P[b][i][j] * v[b][c][j]  (P stride 2048, into qkT buffer)
  gemm_bt<0, true><<<512, 256, 0, stream>>>(
      (const unsigned short*)Sbuf, 2048, 2048LL * 1024, vbuf, 1024, 512LL * 1024,
      qkT, 512, 1024LL * 512, nullptr, nullptr, 0, 1024, 512, 1024, 8, 4);

  // GEMM5: out[b][o][p] = sum_c wproj[o][c] * Ot[b][p][c] + proj_b[o] + x[b][o][p]
  gemm_bt<3, false><<<512, 256, 0, stream>>>(
      wproj, 512, 0, qkT, 512, 1024LL * 512,
      out, 1024, 512LL * 1024, proj_b, x, 512LL * 1024, 512, 1024, 512, 4, 8);
}